// Round 1
// baseline (332.783 us; speedup 1.0000x reference)
//
#include <hip/hip_runtime.h>
#include <stdint.h>

#define DIM 1024
#define SEQ 2048
#define NB 4

typedef unsigned short u16;
typedef __bf16 bf16x8 __attribute__((ext_vector_type(8)));
typedef float floatx4 __attribute__((ext_vector_type(4)));

__device__ __forceinline__ u16 f32_to_bf16(float f) {
  union { float f; unsigned u; } v; v.f = f;
  unsigned r = v.u + 0x7FFFu + ((v.u >> 16) & 1u);
  return (u16)(r >> 16);
}

__device__ __forceinline__ void async16(const void* g, void* l) {
  __builtin_amdgcn_global_load_lds(
      (__attribute__((address_space(1))) unsigned int*)g,
      (__attribute__((address_space(3))) unsigned int*)l, 16, 0, 0);
}

// ---------------- convert x fp32 -> bf16 ----------------
__global__ __launch_bounds__(256) void k_cvt(const float* __restrict__ src,
                                             u16* __restrict__ dst, int n4) {
  int i = blockIdx.x * blockDim.x + threadIdx.x;
  if (i >= n4) return;
  float4 v = ((const float4*)src)[i];
  ushort4 o;
  o.x = f32_to_bf16(v.x); o.y = f32_to_bf16(v.y);
  o.z = f32_to_bf16(v.z); o.w = f32_to_bf16(v.w);
  ((ushort4*)dst)[i] = o;
}

// ---------------- transpose fp32 [R][C] -> bf16 [C][R] ----------------
__global__ void k_tr_f32(const float* __restrict__ src, u16* __restrict__ dst,
                         int R, int C) {
  __shared__ u16 tile[32][33];
  int c0 = blockIdx.x * 32, r0 = blockIdx.y * 32;
  int tx = threadIdx.x, ty = threadIdx.y;
  #pragma unroll
  for (int dy = 0; dy < 32; dy += 8)
    tile[ty + dy][tx] = f32_to_bf16(src[(size_t)(r0 + ty + dy) * C + c0 + tx]);
  __syncthreads();
  #pragma unroll
  for (int dy = 0; dy < 32; dy += 8)
    dst[(size_t)(c0 + ty + dy) * R + r0 + tx] = tile[tx][ty + dy];
}

// ---------------- transpose bf16 [R][C] -> bf16 [C][R], batched ----------------
__global__ void k_tr_b16(const u16* __restrict__ src, u16* __restrict__ dst,
                         int R, int C) {
  src += (size_t)blockIdx.z * R * C;
  dst += (size_t)blockIdx.z * R * C;
  __shared__ u16 tile[32][33];
  int c0 = blockIdx.x * 32, r0 = blockIdx.y * 32;
  int tx = threadIdx.x, ty = threadIdx.y;
  #pragma unroll
  for (int dy = 0; dy < 32; dy += 8)
    tile[ty + dy][tx] = src[(size_t)(r0 + ty + dy) * C + c0 + tx];
  __syncthreads();
  #pragma unroll
  for (int dy = 0; dy < 32; dy += 8)
    dst[(size_t)(c0 + ty + dy) * R + r0 + tx] = tile[tx][ty + dy];
}

// ---------------- 128x128 MFMA GEMM core (A[m][k], Bt[n][k], bf16) ----------------
// Block = 256 threads (4 waves, 2x2 of 64x64). BK=64. Packed LDS tiles staged
// via global_load_lds width=16 (wave-uniform LDS base + lane*16).
__device__ __forceinline__ void mfma_core(const u16* __restrict__ A, int lda,
                                          const u16* __restrict__ Bt, int ldb,
                                          int ktiles, u16* lds,
                                          floatx4 acc[4][4]) {
  const int tid = threadIdx.x;
  const int lane = tid & 63;
  const int wid = tid >> 6;
  u16* lds_a = lds;            // 128 x 64
  u16* lds_b = lds + 8192;     // 128 x 64 (n-major)

  const u16* ag = A + (size_t)(wid * 32 + (lane >> 3)) * lda + (lane & 7) * 8;
  const u16* bg = Bt + (size_t)(wid * 32 + (lane >> 3)) * ldb + (lane & 7) * 8;
  u16* la = lds_a + wid * 2048;  // wave-uniform
  u16* lb = lds_b + wid * 2048;

  const int wm = (wid >> 1) * 64, wn = (wid & 1) * 64;
  const int lrow = lane & 15, quad = lane >> 4;
  const u16* pa = lds_a + (wm + lrow) * 64 + quad * 8;
  const u16* pb = lds_b + (wn + lrow) * 64 + quad * 8;

  for (int kt = 0; kt < ktiles; ++kt) {
    #pragma unroll
    for (int c = 0; c < 4; ++c) {
      async16(ag + (size_t)c * 8 * lda, la + c * 512);
      async16(bg + (size_t)c * 8 * ldb, lb + c * 512);
    }
    ag += 64; bg += 64;
    __syncthreads();   // drains vmcnt (global_load_lds) before ds_read
    #pragma unroll
    for (int ks = 0; ks < 2; ++ks) {
      bf16x8 af[4], bfr[4];
      #pragma unroll
      for (int t = 0; t < 4; ++t) af[t] = *(const bf16x8*)(pa + t * 1024 + ks * 32);
      #pragma unroll
      for (int t = 0; t < 4; ++t) bfr[t] = *(const bf16x8*)(pb + t * 1024 + ks * 32);
      #pragma unroll
      for (int i = 0; i < 4; ++i)
        #pragma unroll
        for (int j = 0; j < 4; ++j)
          acc[i][j] = __builtin_amdgcn_mfma_f32_16x16x32_bf16(af[i], bfr[j],
                                                              acc[i][j], 0, 0, 0);
    }
    __syncthreads();
  }
}

// ---------------- QKV projection: q/k/v = x @ W, bf16 out ----------------
__global__ __launch_bounds__(256) void k_proj(const u16* __restrict__ xb,
                                              const u16* __restrict__ wts,
                                              u16* __restrict__ qkv) {
  __shared__ u16 lds[16384];
  const int n0 = blockIdx.x * 128, m0 = blockIdx.y * 128, z = blockIdx.z;
  floatx4 acc[4][4] = {};
  mfma_core(xb + (size_t)m0 * DIM, DIM,
            wts + (size_t)z * DIM * DIM + (size_t)n0 * DIM, DIM,
            DIM / 64, lds, acc);
  const int lane = threadIdx.x & 63, wid = threadIdx.x >> 6;
  const int wm = (wid >> 1) * 64, wn = (wid & 1) * 64;
  const int lrow = lane & 15, quad = lane >> 4;
  u16* C = qkv + (size_t)z * (NB * SEQ * DIM)
               + (size_t)(m0 + wm + quad * 4) * DIM + n0 + wn + lrow;
  #pragma unroll
  for (int i = 0; i < 4; ++i)
    #pragma unroll
    for (int r = 0; r < 4; ++r)
      #pragma unroll
      for (int j = 0; j < 4; ++j)
        C[(size_t)(i * 16 + r) * DIM + j * 16] = f32_to_bf16(acc[i][j][r]);
}

// ---------------- scores = (q @ k^T) * scale, lower tiles only ----------------
__global__ __launch_bounds__(256) void k_scores(const u16* __restrict__ q,
                                                const u16* __restrict__ k,
                                                float* __restrict__ w) {
  const int nt = blockIdx.x, mt = blockIdx.y, b = blockIdx.z;
  if (nt > mt) return;  // fully-masked tile: softmax kernel writes the zeros
  __shared__ u16 lds[16384];
  floatx4 acc[4][4] = {};
  mfma_core(q + (size_t)b * SEQ * DIM + (size_t)mt * 128 * DIM, DIM,
            k + (size_t)b * SEQ * DIM + (size_t)nt * 128 * DIM, DIM,
            DIM / 64, lds, acc);
  const int lane = threadIdx.x & 63, wid = threadIdx.x >> 6;
  const int wm = (wid >> 1) * 64, wn = (wid & 1) * 64;
  const int lrow = lane & 15, quad = lane >> 4;
  float* C = w + (size_t)b * SEQ * SEQ
               + (size_t)(mt * 128 + wm + quad * 4) * SEQ + nt * 128 + wn + lrow;
  #pragma unroll
  for (int i = 0; i < 4; ++i)
    #pragma unroll
    for (int r = 0; r < 4; ++r)
      #pragma unroll
      for (int j = 0; j < 4; ++j)
        C[(size_t)(i * 16 + r) * SEQ + j * 16] = acc[i][j][r] * 0.03125f;
}

// ---------------- row softmax: weights fp32 (in-place) + P bf16 ----------------
__global__ __launch_bounds__(256) void k_softmax(float* __restrict__ w,
                                                 u16* __restrict__ P) {
  const int r = blockIdx.x;          // b*SEQ + i
  const int i = r & (SEQ - 1);
  const int len = i + 1;
  float* srow = w + (size_t)r * SEQ;
  u16* prow = P + (size_t)r * SEQ;
  const int tid = threadIdx.x;
  const int lane = tid & 63, wid = tid >> 6;
  __shared__ float rm[4], rs[4];

  float e[8];
  float mx = -1e30f;
  #pragma unroll
  for (int t = 0; t < 8; ++t) {
    int j = tid + t * 256;
    float s = (j < len) ? srow[j] : -1e30f;
    e[t] = s;
    mx = fmaxf(mx, s);
  }
  #pragma unroll
  for (int o = 32; o >= 1; o >>= 1) mx = fmaxf(mx, __shfl_xor(mx, o, 64));
  if (lane == 0) rm[wid] = mx;
  __syncthreads();
  mx = fmaxf(fmaxf(rm[0], rm[1]), fmaxf(rm[2], rm[3]));

  float sum = 0.f;
  #pragma unroll
  for (int t = 0; t < 8; ++t) {
    float v = __expf(e[t] - mx);   // masked lanes: exp(-huge) = 0
    e[t] = v;
    sum += v;
  }
  #pragma unroll
  for (int o = 32; o >= 1; o >>= 1) sum += __shfl_xor(sum, o, 64);
  if (lane == 0) rs[wid] = sum;
  __syncthreads();
  sum = rs[0] + rs[1] + rs[2] + rs[3];
  const float inv = 1.0f / sum;

  #pragma unroll
  for (int t = 0; t < 8; ++t) {
    int j = tid + t * 256;
    float v = (j < len) ? e[t] * inv : 0.f;
    srow[j] = v;                    // full row incl. zeros above diagonal
    prow[j] = f32_to_bf16(v);
  }
}

// ---------------- att_output = P @ v (vT layout), causal K truncation ----------------
__global__ __launch_bounds__(256) void k_pv(const u16* __restrict__ P,
                                            const u16* __restrict__ vT,
                                            float* __restrict__ out) {
  const int nt = blockIdx.x, mt = blockIdx.y, b = blockIdx.z;
  __shared__ u16 lds[16384];
  floatx4 acc[4][4] = {};
  mfma_core(P + (size_t)b * SEQ * SEQ + (size_t)mt * 128 * SEQ, SEQ,
            vT + (size_t)b * DIM * SEQ + (size_t)nt * 128 * SEQ, SEQ,
            2 * (mt + 1), lds, acc);
  const int lane = threadIdx.x & 63, wid = threadIdx.x >> 6;
  const int wm = (wid >> 1) * 64, wn = (wid & 1) * 64;
  const int lrow = lane & 15, quad = lane >> 4;
  float* C = out + (size_t)b * SEQ * DIM
                 + (size_t)(mt * 128 + wm + quad * 4) * DIM + nt * 128 + wn + lrow;
  #pragma unroll
  for (int i = 0; i < 4; ++i)
    #pragma unroll
    for (int r = 0; r < 4; ++r)
      #pragma unroll
      for (int j = 0; j < 4; ++j)
        C[(size_t)(i * 16 + r) * DIM + j * 16] = acc[i][j][r];
}

extern "C" void kernel_launch(void* const* d_in, const int* in_sizes, int n_in,
                              void* d_out, int out_size, void* d_ws, size_t ws_size,
                              hipStream_t stream) {
  const float* x  = (const float*)d_in[0];
  const float* Wq = (const float*)d_in[1];
  const float* Wk = (const float*)d_in[2];
  const float* Wv = (const float*)d_in[3];
  float* att_out = (float*)d_out;                    // [4,2048,1024]
  float* att_w   = (float*)d_out + 8388608;          // [4,2048,2048]

  // workspace layout (bf16 elements); total ~118 MB
  u16* xb  = (u16*)d_ws;            // 8,388,608   x bf16
  u16* wt  = xb + 8388608;          // 3,145,728   Wq^T,Wk^T,Wv^T bf16
  u16* qkv = wt + 3145728;          // 25,165,824  q,k,v bf16
  u16* vT  = qkv + 25165824;        // 8,388,608   v^T per batch
  u16* P   = vT + 8388608;          // 16,777,216  softmax probs bf16

  dim3 tb(32, 8);
  k_cvt<<<8192, 256, 0, stream>>>(x, xb, 8388608 / 4);
  k_tr_f32<<<dim3(32, 32), tb, 0, stream>>>(Wq, wt, DIM, DIM);
  k_tr_f32<<<dim3(32, 32), tb, 0, stream>>>(Wk, wt + 1048576, DIM, DIM);
  k_tr_f32<<<dim3(32, 32), tb, 0, stream>>>(Wv, wt + 2097152, DIM, DIM);
  k_proj<<<dim3(8, 64, 3), 256, 0, stream>>>(xb, wt, qkv);
  k_tr_b16<<<dim3(DIM / 32, SEQ / 32, NB), tb, 0, stream>>>(qkv + 2 * 8388608, vT,
                                                            SEQ, DIM);
  k_scores<<<dim3(16, 16, NB), 256, 0, stream>>>(qkv, qkv + 8388608, att_w);
  k_softmax<<<8192, 256, 0, stream>>>(att_w, P);
  k_pv<<<dim3(8, 16, NB), 256, 0, stream>>>(P, vT, att_out);
}

// Round 2
// 327.540 us; speedup vs baseline: 1.0160x; 1.0160x over previous
//
#include <hip/hip_runtime.h>
#include <stdint.h>

#define DIM 1024
#define SEQ 2048
#define NB 4

typedef unsigned short u16;
typedef __bf16 bf16x8 __attribute__((ext_vector_type(8)));
typedef float floatx4 __attribute__((ext_vector_type(4)));

__device__ __forceinline__ u16 f32_to_bf16(float f) {
  union { float f; unsigned u; } v; v.f = f;
  unsigned r = v.u + 0x7FFFu + ((v.u >> 16) & 1u);
  return (u16)(r >> 16);
}

__device__ __forceinline__ void async16(const void* g, void* l) {
  __builtin_amdgcn_global_load_lds(
      (__attribute__((address_space(1))) unsigned int*)g,
      (__attribute__((address_space(3))) unsigned int*)l, 16, 0, 0);
}

// ---------------- convert x fp32 -> bf16 ----------------
__global__ __launch_bounds__(256) void k_cvt(const float* __restrict__ src,
                                             u16* __restrict__ dst, int n4) {
  int i = blockIdx.x * blockDim.x + threadIdx.x;
  if (i >= n4) return;
  float4 v = ((const float4*)src)[i];
  ushort4 o;
  o.x = f32_to_bf16(v.x); o.y = f32_to_bf16(v.y);
  o.z = f32_to_bf16(v.z); o.w = f32_to_bf16(v.w);
  ((ushort4*)dst)[i] = o;
}

// ---------------- transpose fp32 [R][C] -> bf16 [C][R], 3 weights ----------------
__global__ void k_tr_f32(const float* __restrict__ Wq, const float* __restrict__ Wk,
                         const float* __restrict__ Wv, u16* __restrict__ dst) {
  const int z = blockIdx.z;
  const float* src = (z == 0) ? Wq : (z == 1) ? Wk : Wv;
  u16* d = dst + (size_t)z * DIM * DIM;
  __shared__ u16 tile[32][33];
  int c0 = blockIdx.x * 32, r0 = blockIdx.y * 32;
  int tx = threadIdx.x, ty = threadIdx.y;
  #pragma unroll
  for (int dy = 0; dy < 32; dy += 8)
    tile[ty + dy][tx] = f32_to_bf16(src[(size_t)(r0 + ty + dy) * DIM + c0 + tx]);
  __syncthreads();
  #pragma unroll
  for (int dy = 0; dy < 32; dy += 8)
    d[(size_t)(c0 + ty + dy) * DIM + r0 + tx] = tile[tx][ty + dy];
}

// ---------------- 128x128 MFMA GEMM core (A[m][k], Bt[n][k], bf16) ----------------
__device__ __forceinline__ void mfma_core(const u16* __restrict__ A, int lda,
                                          const u16* __restrict__ Bt, int ldb,
                                          int ktiles, u16* lds,
                                          floatx4 acc[4][4]) {
  const int tid = threadIdx.x;
  const int lane = tid & 63;
  const int wid = tid >> 6;
  u16* lds_a = lds;            // 128 x 64
  u16* lds_b = lds + 8192;     // 128 x 64 (n-major)

  const u16* ag = A + (size_t)(wid * 32 + (lane >> 3)) * lda + (lane & 7) * 8;
  const u16* bg = Bt + (size_t)(wid * 32 + (lane >> 3)) * ldb + (lane & 7) * 8;
  u16* la = lds_a + wid * 2048;  // wave-uniform
  u16* lb = lds_b + wid * 2048;

  const int wm = (wid >> 1) * 64, wn = (wid & 1) * 64;
  const int lrow = lane & 15, quad = lane >> 4;
  const u16* pa = lds_a + (wm + lrow) * 64 + quad * 8;
  const u16* pb = lds_b + (wn + lrow) * 64 + quad * 8;

  for (int kt = 0; kt < ktiles; ++kt) {
    #pragma unroll
    for (int c = 0; c < 4; ++c) {
      async16(ag + (size_t)c * 8 * lda, la + c * 512);
      async16(bg + (size_t)c * 8 * ldb, lb + c * 512);
    }
    ag += 64; bg += 64;
    __syncthreads();
    #pragma unroll
    for (int ks = 0; ks < 2; ++ks) {
      bf16x8 af[4], bfr[4];
      #pragma unroll
      for (int t = 0; t < 4; ++t) af[t] = *(const bf16x8*)(pa + t * 1024 + ks * 32);
      #pragma unroll
      for (int t = 0; t < 4; ++t) bfr[t] = *(const bf16x8*)(pb + t * 1024 + ks * 32);
      #pragma unroll
      for (int i = 0; i < 4; ++i)
        #pragma unroll
        for (int j = 0; j < 4; ++j)
          acc[i][j] = __builtin_amdgcn_mfma_f32_16x16x32_bf16(af[i], bfr[j],
                                                              acc[i][j], 0, 0, 0);
    }
    __syncthreads();
  }
}

// ---------------- q,k = x @ [Wq|Wk], bf16 out ----------------
// XCD swizzle: all 16 n-tiles of an m-tile map to id == mt (mod 8) -> same XCD,
// so the shared A-tile is fetched into one XCD's L2 once.
__global__ __launch_bounds__(256) void k_projqk(const u16* __restrict__ xb,
                                                const u16* __restrict__ wt,
                                                u16* __restrict__ qk) {
  const int x = blockIdx.x;                // [0,1024)
  const int mt = (x >> 7) * 8 + (x & 7);   // [0,64)
  const int nt = (x >> 3) & 15;            // [0,16)
  __shared__ u16 lds[16384];
  floatx4 acc[4][4] = {};
  mfma_core(xb + (size_t)mt * 128 * DIM, DIM,
            wt + (size_t)nt * 128 * DIM, DIM, DIM / 64, lds, acc);
  const int lane = threadIdx.x & 63, wid = threadIdx.x >> 6;
  const int wm = (wid >> 1) * 64, wn = (wid & 1) * 64;
  const int lrow = lane & 15, quad = lane >> 4;
  const int n0 = nt * 128;
  const int z = n0 >> 10;                  // 0 = q, 1 = k
  const int nn = n0 & 1023;
  u16* C = qk + (size_t)z * (NB * SEQ * DIM)
              + (size_t)(mt * 128 + wm + quad * 4) * DIM + nn + wn + lrow;
  #pragma unroll
  for (int i = 0; i < 4; ++i)
    #pragma unroll
    for (int r = 0; r < 4; ++r)
      #pragma unroll
      for (int j = 0; j < 4; ++j)
        C[(size_t)(i * 16 + r) * DIM + j * 16] = f32_to_bf16(acc[i][j][r]);
}

// ---------------- vT = Wv^T @ x^T : A = Wv^T [1024][1024], Bt = xb [8192][1024] ----
// Groups = token tile (nt, 64 groups of 8 m-tiles) -> same XCD shares the x-tile.
__global__ __launch_bounds__(256) void k_projv(const u16* __restrict__ wv,
                                               const u16* __restrict__ xb,
                                               u16* __restrict__ vT) {
  const int x = blockIdx.x;                // [0,512)
  const int nt = (x >> 6) * 8 + (x & 7);   // token tile [0,64)
  const int mt = (x >> 3) & 7;             // v-dim tile [0,8)
  __shared__ u16 lds[16384];
  floatx4 acc[4][4] = {};
  mfma_core(wv + (size_t)mt * 128 * DIM, DIM,
            xb + (size_t)nt * 128 * DIM, DIM, DIM / 64, lds, acc);
  const int lane = threadIdx.x & 63, wid = threadIdx.x >> 6;
  const int wm = (wid >> 1) * 64, wn = (wid & 1) * 64;
  const int lrow = lane & 15, quad = lane >> 4;
  const int t0 = nt * 128;
  const int b = t0 >> 11, s0 = t0 & 2047;  // tile fully within one batch
  u16* C = vT + (size_t)b * (DIM * SEQ)
              + (size_t)(mt * 128 + wm + quad * 4) * SEQ + s0 + wn + lrow;
  #pragma unroll
  for (int i = 0; i < 4; ++i)
    #pragma unroll
    for (int r = 0; r < 4; ++r)
      #pragma unroll
      for (int j = 0; j < 4; ++j)
        C[(size_t)(i * 16 + r) * SEQ + j * 16] = f32_to_bf16(acc[i][j][r]);
}

// ---------------- scores = (q @ k^T) * scale, lower tiles only ----------------
__global__ __launch_bounds__(256) void k_scores(const u16* __restrict__ q,
                                                const u16* __restrict__ k,
                                                float* __restrict__ w) {
  const int x = blockIdx.x, b = blockIdx.z;  // x in [0,1024)
  const int mt = (x >> 7) * 8 + (x & 7);     // [0,16) ... wait: (x>>7) in [0,8)
  const int nt = (x >> 3) & 15;
  const int qt = mt & 15;                    // mt already in [0,64)? no: see below
  // Grid x = 1024 = 8 groups-of-128; mt = (x>>7)*8 + x%8 spans [0,64) but we
  // only have 16 m-tiles -> use 16x16 layout: x in [0,256)*4? Simpler: x<256.
  (void)qt;
  if (x >= 256) return;  // unreachable with grid 256; kept for safety
  const int mt2 = ((x >> 7) * 8 + (x & 7)) & 15;
  (void)mt2;
  // real decode for grid.x == 256: groups of 16 nt per mt, id == mt (mod 8)
  const int mtd = (x >> 7) * 8 + (x & 7);    // [0,16)
  const int ntd = (x >> 3) & 15;             // [0,16)
  if (ntd > mtd) return;
  __shared__ u16 lds[16384];
  floatx4 acc[4][4] = {};
  mfma_core(q + (size_t)b * SEQ * DIM + (size_t)mtd * 128 * DIM, DIM,
            k + (size_t)b * SEQ * DIM + (size_t)ntd * 128 * DIM, DIM,
            DIM / 64, lds, acc);
  const int lane = threadIdx.x & 63, wid = threadIdx.x >> 6;
  const int wm = (wid >> 1) * 64, wn = (wid & 1) * 64;
  const int lrow = lane & 15, quad = lane >> 4;
  float* C = w + (size_t)b * SEQ * SEQ
               + (size_t)(mtd * 128 + wm + quad * 4) * SEQ + ntd * 128 + wn + lrow;
  #pragma unroll
  for (int i = 0; i < 4; ++i)
    #pragma unroll
    for (int r = 0; r < 4; ++r)
      #pragma unroll
      for (int j = 0; j < 4; ++j)
        C[(size_t)(i * 16 + r) * SEQ + j * 16] = acc[i][j][r] * 0.03125f;
  (void)mt; (void)nt;
}

// ---------------- row softmax: weights fp32 (in-place) + P bf16 ----------------
__global__ __launch_bounds__(256) void k_softmax(float* __restrict__ w,
                                                 u16* __restrict__ P) {
  const int r = blockIdx.x;
  const int i = r & (SEQ - 1);
  const int len = i + 1;
  float4* srow = (float4*)(w + (size_t)r * SEQ);
  ushort4* prow = (ushort4*)(P + (size_t)r * SEQ);
  const int tid = threadIdx.x;
  const int lane = tid & 63, wid = tid >> 6;
  __shared__ float rm[4], rs[4];

  float4 e[2];
  float mx = -1e30f;
  #pragma unroll
  for (int u = 0; u < 2; ++u) {
    int q4 = tid + u * 256;          // float4 index in [0,512)
    float4 v = srow[q4];
    int j0 = q4 * 4;
    v.x = (j0 + 0 < len) ? v.x : -1e30f;
    v.y = (j0 + 1 < len) ? v.y : -1e30f;
    v.z = (j0 + 2 < len) ? v.z : -1e30f;
    v.w = (j0 + 3 < len) ? v.w : -1e30f;
    e[u] = v;
    mx = fmaxf(mx, fmaxf(fmaxf(v.x, v.y), fmaxf(v.z, v.w)));
  }
  #pragma unroll
  for (int o = 32; o >= 1; o >>= 1) mx = fmaxf(mx, __shfl_xor(mx, o, 64));
  if (lane == 0) rm[wid] = mx;
  __syncthreads();
  mx = fmaxf(fmaxf(rm[0], rm[1]), fmaxf(rm[2], rm[3]));

  float sum = 0.f;
  #pragma unroll
  for (int u = 0; u < 2; ++u) {
    e[u].x = __expf(e[u].x - mx);
    e[u].y = __expf(e[u].y - mx);
    e[u].z = __expf(e[u].z - mx);
    e[u].w = __expf(e[u].w - mx);
    sum += e[u].x + e[u].y + e[u].z + e[u].w;
  }
  #pragma unroll
  for (int o = 32; o >= 1; o >>= 1) sum += __shfl_xor(sum, o, 64);
  if (lane == 0) rs[wid] = sum;
  __syncthreads();
  sum = rs[0] + rs[1] + rs[2] + rs[3];
  const float inv = 1.0f / sum;

  #pragma unroll
  for (int u = 0; u < 2; ++u) {
    int q4 = tid + u * 256;
    int j0 = q4 * 4;
    float4 v;
    v.x = (j0 + 0 < len) ? e[u].x * inv : 0.f;
    v.y = (j0 + 1 < len) ? e[u].y * inv : 0.f;
    v.z = (j0 + 2 < len) ? e[u].z * inv : 0.f;
    v.w = (j0 + 3 < len) ? e[u].w * inv : 0.f;
    srow[q4] = v;
    ushort4 p;
    p.x = f32_to_bf16(v.x); p.y = f32_to_bf16(v.y);
    p.z = f32_to_bf16(v.z); p.w = f32_to_bf16(v.w);
    prow[q4] = p;
  }
}

// ---------------- att_output = P @ v (vT layout), causal K truncation ----------------
// Groups = (mt): 8 nt blocks with id == mt (mod 8) share the P row-tile.
__global__ __launch_bounds__(256) void k_pv(const u16* __restrict__ P,
                                            const u16* __restrict__ vT,
                                            float* __restrict__ out) {
  const int x = blockIdx.x, b = blockIdx.z;  // x in [0,128)
  const int mt = (x >> 6) * 8 + (x & 7);     // [0,16)
  const int nt = (x >> 3) & 7;               // [0,8)
  __shared__ u16 lds[16384];
  floatx4 acc[4][4] = {};
  mfma_core(P + (size_t)b * SEQ * SEQ + (size_t)mt * 128 * SEQ, SEQ,
            vT + (size_t)b * DIM * SEQ + (size_t)nt * 128 * SEQ, SEQ,
            2 * (mt + 1), lds, acc);
  const int lane = threadIdx.x & 63, wid = threadIdx.x >> 6;
  const int wm = (wid >> 1) * 64, wn = (wid & 1) * 64;
  const int lrow = lane & 15, quad = lane >> 4;
  float* C = out + (size_t)b * SEQ * DIM
                 + (size_t)(mt * 128 + wm + quad * 4) * DIM + nt * 128 + wn + lrow;
  #pragma unroll
  for (int i = 0; i < 4; ++i)
    #pragma unroll
    for (int r = 0; r < 4; ++r)
      #pragma unroll
      for (int j = 0; j < 4; ++j)
        C[(size_t)(i * 16 + r) * DIM + j * 16] = acc[i][j][r];
}

extern "C" void kernel_launch(void* const* d_in, const int* in_sizes, int n_in,
                              void* d_out, int out_size, void* d_ws, size_t ws_size,
                              hipStream_t stream) {
  const float* x  = (const float*)d_in[0];
  const float* Wq = (const float*)d_in[1];
  const float* Wk = (const float*)d_in[2];
  const float* Wv = (const float*)d_in[3];
  float* att_out = (float*)d_out;                    // [4,2048,1024]
  float* att_w   = (float*)d_out + 8388608;          // [4,2048,2048]

  // workspace layout (bf16 elements); ~107 MB
  u16* xb = (u16*)d_ws;             // 8,388,608   x bf16
  u16* wt = xb + 8388608;           // 3,145,728   Wq^T,Wk^T,Wv^T bf16
  u16* qk = wt + 3145728;           // 16,777,216  q,k bf16
  u16* vT = qk + 16777216;          // 8,388,608   v^T per batch
  u16* P  = vT + 8388608;           // 16,777,216  softmax probs bf16

  dim3 tb(32, 8);
  k_cvt<<<8192, 256, 0, stream>>>(x, xb, 8388608 / 4);
  k_tr_f32<<<dim3(32, 32, 3), tb, 0, stream>>>(Wq, Wk, Wv, wt);
  k_projqk<<<1024, 256, 0, stream>>>(xb, wt, qk);
  k_projv<<<512, 256, 0, stream>>>(wt + 2097152, xb, vT);
  k_scores<<<dim3(256, 1, NB), 256, 0, stream>>>(qk, qk + 8388608, att_w);
  k_softmax<<<8192, 256, 0, stream>>>(att_w, P);
  k_pv<<<dim3(128, 1, NB), 256, 0, stream>>>(P, vT, att_out);
}

// Round 3
// 316.702 us; speedup vs baseline: 1.0508x; 1.0342x over previous
//
#include <hip/hip_runtime.h>
#include <stdint.h>

#define DIM 1024
#define SEQ 2048
#define NB 4

typedef unsigned short u16;
typedef __bf16 bf16x8 __attribute__((ext_vector_type(8)));
typedef float floatx4 __attribute__((ext_vector_type(4)));

__device__ __forceinline__ u16 f32_to_bf16(float f) {
  union { float f; unsigned u; } v; v.f = f;
  unsigned r = v.u + 0x7FFFu + ((v.u >> 16) & 1u);
  return (u16)(r >> 16);
}

__device__ __forceinline__ void async16(const void* g, void* l) {
  __builtin_amdgcn_global_load_lds(
      (__attribute__((address_space(1))) unsigned int*)g,
      (__attribute__((address_space(3))) unsigned int*)l, 16, 0, 0);
}

// ---------------- convert x fp32 -> bf16 ----------------
__global__ __launch_bounds__(256) void k_cvt(const float* __restrict__ src,
                                             u16* __restrict__ dst, int n4) {
  int i = blockIdx.x * blockDim.x + threadIdx.x;
  if (i >= n4) return;
  float4 v = ((const float4*)src)[i];
  ushort4 o;
  o.x = f32_to_bf16(v.x); o.y = f32_to_bf16(v.y);
  o.z = f32_to_bf16(v.z); o.w = f32_to_bf16(v.w);
  ((ushort4*)dst)[i] = o;
}

// ---------------- transpose fp32 [R][C] -> bf16 [C][R], 3 weights ----------------
__global__ void k_tr_f32(const float* __restrict__ Wq, const float* __restrict__ Wk,
                         const float* __restrict__ Wv, u16* __restrict__ dst) {
  const int z = blockIdx.z;
  const float* src = (z == 0) ? Wq : (z == 1) ? Wk : Wv;
  u16* d = dst + (size_t)z * DIM * DIM;
  __shared__ u16 tile[32][33];
  int c0 = blockIdx.x * 32, r0 = blockIdx.y * 32;
  int tx = threadIdx.x, ty = threadIdx.y;
  #pragma unroll
  for (int dy = 0; dy < 32; dy += 8)
    tile[ty + dy][tx] = f32_to_bf16(src[(size_t)(r0 + ty + dy) * DIM + c0 + tx]);
  __syncthreads();
  #pragma unroll
  for (int dy = 0; dy < 32; dy += 8)
    d[(size_t)(c0 + ty + dy) * DIM + r0 + tx] = tile[tx][ty + dy];
}

// ---------------- 128x128 MFMA GEMM core (A[m][k], Bt[n][k], bf16) ----------------
__device__ __forceinline__ void mfma_core(const u16* __restrict__ A, int lda,
                                          const u16* __restrict__ Bt, int ldb,
                                          int ktiles, u16* lds,
                                          floatx4 acc[4][4]) {
  const int tid = threadIdx.x;
  const int lane = tid & 63;
  const int wid = tid >> 6;
  u16* lds_a = lds;            // 128 x 64
  u16* lds_b = lds + 8192;     // 128 x 64 (n-major)

  const u16* ag = A + (size_t)(wid * 32 + (lane >> 3)) * lda + (lane & 7) * 8;
  const u16* bg = Bt + (size_t)(wid * 32 + (lane >> 3)) * ldb + (lane & 7) * 8;
  u16* la = lds_a + wid * 2048;  // wave-uniform
  u16* lb = lds_b + wid * 2048;

  const int wm = (wid >> 1) * 64, wn = (wid & 1) * 64;
  const int lrow = lane & 15, quad = lane >> 4;
  const u16* pa = lds_a + (wm + lrow) * 64 + quad * 8;
  const u16* pb = lds_b + (wn + lrow) * 64 + quad * 8;

  for (int kt = 0; kt < ktiles; ++kt) {
    #pragma unroll
    for (int c = 0; c < 4; ++c) {
      async16(ag + (size_t)c * 8 * lda, la + c * 512);
      async16(bg + (size_t)c * 8 * ldb, lb + c * 512);
    }
    ag += 64; bg += 64;
    __syncthreads();
    #pragma unroll
    for (int ks = 0; ks < 2; ++ks) {
      bf16x8 af[4], bfr[4];
      #pragma unroll
      for (int t = 0; t < 4; ++t) af[t] = *(const bf16x8*)(pa + t * 1024 + ks * 32);
      #pragma unroll
      for (int t = 0; t < 4; ++t) bfr[t] = *(const bf16x8*)(pb + t * 1024 + ks * 32);
      #pragma unroll
      for (int i = 0; i < 4; ++i)
        #pragma unroll
        for (int j = 0; j < 4; ++j)
          acc[i][j] = __builtin_amdgcn_mfma_f32_16x16x32_bf16(af[i], bfr[j],
                                                              acc[i][j], 0, 0, 0);
    }
    __syncthreads();
  }
}

// ---------------- q,k = x @ [Wq|Wk], bf16 out ----------------
// XCD grouping: all 16 n-tiles of an m-tile land on id == mt (mod 8).
__global__ __launch_bounds__(256) void k_projqk(const u16* __restrict__ xb,
                                                const u16* __restrict__ wt,
                                                u16* __restrict__ qk) {
  const int x = blockIdx.x;                // [0,1024)
  const int mt = (x >> 7) * 8 + (x & 7);   // [0,64)
  const int nt = (x >> 3) & 15;            // [0,16)
  __shared__ u16 lds[16384];
  floatx4 acc[4][4] = {};
  mfma_core(xb + (size_t)mt * 128 * DIM, DIM,
            wt + (size_t)nt * 128 * DIM, DIM, DIM / 64, lds, acc);
  const int lane = threadIdx.x & 63, wid = threadIdx.x >> 6;
  const int wm = (wid >> 1) * 64, wn = (wid & 1) * 64;
  const int lrow = lane & 15, quad = lane >> 4;
  const int n0 = nt * 128;
  const int z = n0 >> 10;                  // 0 = q, 1 = k
  const int nn = n0 & 1023;
  u16* C = qk + (size_t)z * (NB * SEQ * DIM)
              + (size_t)(mt * 128 + wm + quad * 4) * DIM + nn + wn + lrow;
  #pragma unroll
  for (int i = 0; i < 4; ++i)
    #pragma unroll
    for (int r = 0; r < 4; ++r)
      #pragma unroll
      for (int j = 0; j < 4; ++j)
        C[(size_t)(i * 16 + r) * DIM + j * 16] = f32_to_bf16(acc[i][j][r]);
}

// ---------------- vT = Wv^T @ x^T ----------------
__global__ __launch_bounds__(256) void k_projv(const u16* __restrict__ wv,
                                               const u16* __restrict__ xb,
                                               u16* __restrict__ vT) {
  const int x = blockIdx.x;                // [0,512)
  const int nt = (x >> 6) * 8 + (x & 7);   // token tile [0,64)
  const int mt = (x >> 3) & 7;             // v-dim tile [0,8)
  __shared__ u16 lds[16384];
  floatx4 acc[4][4] = {};
  mfma_core(wv + (size_t)mt * 128 * DIM, DIM,
            xb + (size_t)nt * 128 * DIM, DIM, DIM / 64, lds, acc);
  const int lane = threadIdx.x & 63, wid = threadIdx.x >> 6;
  const int wm = (wid >> 1) * 64, wn = (wid & 1) * 64;
  const int lrow = lane & 15, quad = lane >> 4;
  const int t0 = nt * 128;
  const int b = t0 >> 11, s0 = t0 & 2047;
  u16* C = vT + (size_t)b * (DIM * SEQ)
              + (size_t)(mt * 128 + wm + quad * 4) * SEQ + s0 + wn + lrow;
  #pragma unroll
  for (int i = 0; i < 4; ++i)
    #pragma unroll
    for (int r = 0; r < 4; ++r)
      #pragma unroll
      for (int j = 0; j < 4; ++j)
        C[(size_t)(i * 16 + r) * SEQ + j * 16] = f32_to_bf16(acc[i][j][r]);
}

// ---------------- scores = (q @ k^T) * scale, lower tiles only ----------------
// b folded into blockIdx.x: xcd = b*2 + (mt&1) so one XCD owns one batch's
// even-or-odd q-row-tiles; its k working set (4 MB/batch) fits the XCD L2.
// nt is the fastest-varying field -> q-tile reused across 16 consecutive ids.
__global__ __launch_bounds__(256) void k_scores(const u16* __restrict__ q,
                                                const u16* __restrict__ k,
                                                float* __restrict__ w) {
  const int id = blockIdx.x;               // [0,1024)
  const int b = (id & 7) >> 1;             // [0,4)
  const int mtl = id & 1;
  const int rest = id >> 3;                // [0,128)
  const int mt = (rest >> 4) * 2 + mtl;    // [0,16)
  const int nt = rest & 15;                // [0,16)
  if (nt > mt) return;
  __shared__ u16 lds[16384];
  floatx4 acc[4][4] = {};
  mfma_core(q + (size_t)b * SEQ * DIM + (size_t)mt * 128 * DIM, DIM,
            k + (size_t)b * SEQ * DIM + (size_t)nt * 128 * DIM, DIM,
            DIM / 64, lds, acc);
  const int lane = threadIdx.x & 63, wid = threadIdx.x >> 6;
  const int wm = (wid >> 1) * 64, wn = (wid & 1) * 64;
  const int lrow = lane & 15, quad = lane >> 4;
  float* C = w + (size_t)b * SEQ * SEQ
               + (size_t)(mt * 128 + wm + quad * 4) * SEQ + nt * 128 + wn + lrow;
  #pragma unroll
  for (int i = 0; i < 4; ++i)
    #pragma unroll
    for (int r = 0; r < 4; ++r)
      #pragma unroll
      for (int j = 0; j < 4; ++j)
        C[(size_t)(i * 16 + r) * SEQ + j * 16] = acc[i][j][r] * 0.03125f;
}

// ---------------- row softmax: weights fp32 (in-place) + P bf16 ----------------
// Reads only the causal prefix; writes P only up to the 128-tile boundary
// (k_pv's K-loop never reads past it).
__global__ __launch_bounds__(256) void k_softmax(float* __restrict__ w,
                                                 u16* __restrict__ P) {
  const int r = blockIdx.x;
  const int i = r & (SEQ - 1);
  const int len = i + 1;
  const int plen4 = (((i >> 7) + 1) << 7) >> 2;   // P write bound / float4
  float4* srow = (float4*)(w + (size_t)r * SEQ);
  ushort4* prow = (ushort4*)(P + (size_t)r * SEQ);
  const int tid = threadIdx.x;
  const int lane = tid & 63, wid = tid >> 6;
  __shared__ float rm[4], rs[4];

  float4 e[2];
  float mx = -1e30f;
  #pragma unroll
  for (int u = 0; u < 2; ++u) {
    int q4 = tid + u * 256;
    int j0 = q4 * 4;
    float4 v = make_float4(-1e30f, -1e30f, -1e30f, -1e30f);
    if (j0 < len) {
      v = srow[q4];
      v.x = (j0 + 0 < len) ? v.x : -1e30f;
      v.y = (j0 + 1 < len) ? v.y : -1e30f;
      v.z = (j0 + 2 < len) ? v.z : -1e30f;
      v.w = (j0 + 3 < len) ? v.w : -1e30f;
    }
    e[u] = v;
    mx = fmaxf(mx, fmaxf(fmaxf(v.x, v.y), fmaxf(v.z, v.w)));
  }
  #pragma unroll
  for (int o = 32; o >= 1; o >>= 1) mx = fmaxf(mx, __shfl_xor(mx, o, 64));
  if (lane == 0) rm[wid] = mx;
  __syncthreads();
  mx = fmaxf(fmaxf(rm[0], rm[1]), fmaxf(rm[2], rm[3]));

  float sum = 0.f;
  #pragma unroll
  for (int u = 0; u < 2; ++u) {
    e[u].x = __expf(e[u].x - mx);
    e[u].y = __expf(e[u].y - mx);
    e[u].z = __expf(e[u].z - mx);
    e[u].w = __expf(e[u].w - mx);
    sum += e[u].x + e[u].y + e[u].z + e[u].w;
  }
  #pragma unroll
  for (int o = 32; o >= 1; o >>= 1) sum += __shfl_xor(sum, o, 64);
  if (lane == 0) rs[wid] = sum;
  __syncthreads();
  sum = rs[0] + rs[1] + rs[2] + rs[3];
  const float inv = 1.0f / sum;

  #pragma unroll
  for (int u = 0; u < 2; ++u) {
    int q4 = tid + u * 256;
    int j0 = q4 * 4;
    float4 v;
    v.x = (j0 + 0 < len) ? e[u].x * inv : 0.f;
    v.y = (j0 + 1 < len) ? e[u].y * inv : 0.f;
    v.z = (j0 + 2 < len) ? e[u].z * inv : 0.f;
    v.w = (j0 + 3 < len) ? e[u].w * inv : 0.f;
    srow[q4] = v;                   // full fp32 row incl. zeros (output!)
    if (q4 < plen4) {
      ushort4 p;
      p.x = f32_to_bf16(v.x); p.y = f32_to_bf16(v.y);
      p.z = f32_to_bf16(v.z); p.w = f32_to_bf16(v.w);
      prow[q4] = p;
    }
  }
}

// ---------------- att_output = P @ v (vT layout), causal K truncation ----------------
// Same batch-folded swizzle: xcd = b*2 + (mt&1); vT (4 MB/batch) stays L2-hot,
// P row-tile reused by the 8 nt blocks of the same group.
__global__ __launch_bounds__(256) void k_pv(const u16* __restrict__ P,
                                            const u16* __restrict__ vT,
                                            float* __restrict__ out) {
  const int id = blockIdx.x;               // [0,512)
  const int b = (id & 7) >> 1;             // [0,4)
  const int mtl = id & 1;
  const int rest = id >> 3;                // [0,64)
  const int mt = (rest >> 3) * 2 + mtl;    // [0,16)
  const int nt = rest & 7;                 // [0,8)
  __shared__ u16 lds[16384];
  floatx4 acc[4][4] = {};
  mfma_core(P + (size_t)b * SEQ * SEQ + (size_t)mt * 128 * SEQ, SEQ,
            vT + (size_t)b * DIM * SEQ + (size_t)nt * 128 * SEQ, SEQ,
            2 * (mt + 1), lds, acc);
  const int lane = threadIdx.x & 63, wid = threadIdx.x >> 6;
  const int wm = (wid >> 1) * 64, wn = (wid & 1) * 64;
  const int lrow = lane & 15, quad = lane >> 4;
  float* C = out + (size_t)b * SEQ * DIM
                 + (size_t)(mt * 128 + wm + quad * 4) * DIM + nt * 128 + wn + lrow;
  #pragma unroll
  for (int i = 0; i < 4; ++i)
    #pragma unroll
    for (int r = 0; r < 4; ++r)
      #pragma unroll
      for (int j = 0; j < 4; ++j)
        C[(size_t)(i * 16 + r) * DIM + j * 16] = acc[i][j][r];
}

extern "C" void kernel_launch(void* const* d_in, const int* in_sizes, int n_in,
                              void* d_out, int out_size, void* d_ws, size_t ws_size,
                              hipStream_t stream) {
  const float* x  = (const float*)d_in[0];
  const float* Wq = (const float*)d_in[1];
  const float* Wk = (const float*)d_in[2];
  const float* Wv = (const float*)d_in[3];
  float* att_out = (float*)d_out;                    // [4,2048,1024]
  float* att_w   = (float*)d_out + 8388608;          // [4,2048,2048]

  // workspace layout (bf16 elements); ~107 MB
  u16* xb = (u16*)d_ws;             // 8,388,608   x bf16
  u16* wt = xb + 8388608;           // 3,145,728   Wq^T,Wk^T,Wv^T bf16
  u16* qk = wt + 3145728;           // 16,777,216  q,k bf16
  u16* vT = qk + 16777216;          // 8,388,608   v^T per batch
  u16* P  = vT + 8388608;           // 16,777,216  softmax probs bf16

  dim3 tb(32, 8);
  k_cvt<<<8192, 256, 0, stream>>>(x, xb, 8388608 / 4);
  k_tr_f32<<<dim3(32, 32, 3), tb, 0, stream>>>(Wq, Wk, Wv, wt);
  k_projqk<<<1024, 256, 0, stream>>>(xb, wt, qk);
  k_projv<<<512, 256, 0, stream>>>(wt + 2097152, xb, vT);
  k_scores<<<1024, 256, 0, stream>>>(qk, qk + 8388608, att_w);
  k_softmax<<<8192, 256, 0, stream>>>(att_w, P);
  k_pv<<<512, 256, 0, stream>>>(P, vT, att_out);
}

// Round 4
// 304.866 us; speedup vs baseline: 1.0916x; 1.0388x over previous
//
#include <hip/hip_runtime.h>
#include <stdint.h>

#define DIM 1024
#define SEQ 2048
#define NB 4

typedef unsigned short u16;
typedef __bf16 bf16x8 __attribute__((ext_vector_type(8)));
typedef float floatx4 __attribute__((ext_vector_type(4)));

__device__ __forceinline__ u16 f32_to_bf16(float f) {
  union { float f; unsigned u; } v; v.f = f;
  unsigned r = v.u + 0x7FFFu + ((v.u >> 16) & 1u);
  return (u16)(r >> 16);
}

__device__ __forceinline__ void async16(const void* g, void* l) {
  __builtin_amdgcn_global_load_lds(
      (__attribute__((address_space(1))) unsigned int*)g,
      (__attribute__((address_space(3))) unsigned int*)l, 16, 0, 0);
}

// ---------------- prep: x fp32->bf16  +  W{q,k,v} transpose->bf16 ----------------
// Independent work fused into one launch so the tails overlap.
__global__ __launch_bounds__(256) void k_prep(const float* __restrict__ x,
                                              const float* __restrict__ Wq,
                                              const float* __restrict__ Wk,
                                              const float* __restrict__ Wv,
                                              u16* __restrict__ xb,
                                              u16* __restrict__ wt) {
  __shared__ u16 tile[32][33];
  const int bid = blockIdx.x;
  const int tid = threadIdx.x;
  if (bid < 8192) {                       // cvt: 8192 blocks x 256 x float4
    int i = bid * 256 + tid;
    float4 v = ((const float4*)x)[i];
    ushort4 o;
    o.x = f32_to_bf16(v.x); o.y = f32_to_bf16(v.y);
    o.z = f32_to_bf16(v.z); o.w = f32_to_bf16(v.w);
    ((ushort4*)xb)[i] = o;
  } else {                                // transpose: 3 x 1024 tile-blocks
    int t = bid - 8192;
    int z = t >> 10;
    int ti = t & 1023;
    int c0 = (ti & 31) * 32, r0 = (ti >> 5) * 32;
    const float* src = (z == 0) ? Wq : (z == 1) ? Wk : Wv;
    u16* d = wt + (size_t)z * DIM * DIM;
    int tx = tid & 31, ty = tid >> 5;     // 32 x 8
    #pragma unroll
    for (int dy = 0; dy < 32; dy += 8)
      tile[ty + dy][tx] = f32_to_bf16(src[(size_t)(r0 + ty + dy) * DIM + c0 + tx]);
    __syncthreads();
    #pragma unroll
    for (int dy = 0; dy < 32; dy += 8)
      d[(size_t)(c0 + ty + dy) * DIM + r0 + tx] = tile[tx][ty + dy];
  }
}

// ---------------- 128x128 MFMA GEMM core (A[m][k], Bt[n][k], bf16) ----------------
__device__ __forceinline__ void mfma_core(const u16* __restrict__ A, int lda,
                                          const u16* __restrict__ Bt, int ldb,
                                          int ktiles, u16* lds,
                                          floatx4 acc[4][4]) {
  const int tid = threadIdx.x;
  const int lane = tid & 63;
  const int wid = tid >> 6;
  u16* lds_a = lds;            // 128 x 64
  u16* lds_b = lds + 8192;     // 128 x 64 (n-major)

  const u16* ag = A + (size_t)(wid * 32 + (lane >> 3)) * lda + (lane & 7) * 8;
  const u16* bg = Bt + (size_t)(wid * 32 + (lane >> 3)) * ldb + (lane & 7) * 8;
  u16* la = lds_a + wid * 2048;  // wave-uniform
  u16* lb = lds_b + wid * 2048;

  const int wm = (wid >> 1) * 64, wn = (wid & 1) * 64;
  const int lrow = lane & 15, quad = lane >> 4;
  const u16* pa = lds_a + (wm + lrow) * 64 + quad * 8;
  const u16* pb = lds_b + (wn + lrow) * 64 + quad * 8;

  for (int kt = 0; kt < ktiles; ++kt) {
    #pragma unroll
    for (int c = 0; c < 4; ++c) {
      async16(ag + (size_t)c * 8 * lda, la + c * 512);
      async16(bg + (size_t)c * 8 * ldb, lb + c * 512);
    }
    ag += 64; bg += 64;
    __syncthreads();
    #pragma unroll
    for (int ks = 0; ks < 2; ++ks) {
      bf16x8 af[4], bfr[4];
      #pragma unroll
      for (int t = 0; t < 4; ++t) af[t] = *(const bf16x8*)(pa + t * 1024 + ks * 32);
      #pragma unroll
      for (int t = 0; t < 4; ++t) bfr[t] = *(const bf16x8*)(pb + t * 1024 + ks * 32);
      #pragma unroll
      for (int i = 0; i < 4; ++i)
        #pragma unroll
        for (int j = 0; j < 4; ++j)
          acc[i][j] = __builtin_amdgcn_mfma_f32_16x16x32_bf16(af[i], bfr[j],
                                                              acc[i][j], 0, 0, 0);
    }
    __syncthreads();
  }
}

// ---------------- all projections: q,k (= x@W) and vT (= Wv^T@x^T) ----------------
// id = z2*512 + r; z2 in {0:q, 1:k, 2:vT}. id%8 = r%8 = (row-group)&7 so the
// 8 blocks sharing an A-tile (z2<2: x row tile; z2==2: x token tile as Bt)
// land on one XCD.
__global__ __launch_bounds__(256) void k_proj(const u16* __restrict__ xb,
                                              const u16* __restrict__ wt,
                                              u16* __restrict__ qk,
                                              u16* __restrict__ vT) {
  const int id = blockIdx.x;               // [0,1536)
  const int z2 = id >> 9;                  // 0,1,2
  const int r = id & 511;
  const int g = (r >> 6) * 8 + (r & 7);    // [0,64) shared-tile group
  const int h = (r >> 3) & 7;              // [0,8)
  __shared__ u16 lds[16384];
  floatx4 acc[4][4] = {};
  const u16 *A, *Bt;
  if (z2 < 2) {
    A = xb + (size_t)g * 128 * DIM;
    Bt = wt + (size_t)z2 * DIM * DIM + (size_t)h * 128 * DIM;
  } else {
    A = wt + (size_t)2 * DIM * DIM + (size_t)h * 128 * DIM;
    Bt = xb + (size_t)g * 128 * DIM;
  }
  mfma_core(A, DIM, Bt, DIM, DIM / 64, lds, acc);
  const int lane = threadIdx.x & 63, wid = threadIdx.x >> 6;
  const int wm = (wid >> 1) * 64, wn = (wid & 1) * 64;
  const int lrow = lane & 15, quad = lane >> 4;
  if (z2 < 2) {
    u16* C = qk + (size_t)z2 * (NB * SEQ * DIM)
                + (size_t)(g * 128 + wm + quad * 4) * DIM + h * 128 + wn + lrow;
    #pragma unroll
    for (int i = 0; i < 4; ++i)
      #pragma unroll
      for (int rr = 0; rr < 4; ++rr)
        #pragma unroll
        for (int j = 0; j < 4; ++j)
          C[(size_t)(i * 16 + rr) * DIM + j * 16] = f32_to_bf16(acc[i][j][rr]);
  } else {
    const int t0 = g * 128;
    const int b = t0 >> 11, s0 = t0 & 2047;
    u16* C = vT + (size_t)b * (DIM * SEQ)
                + (size_t)(h * 128 + wm + quad * 4) * SEQ + s0 + wn + lrow;
    #pragma unroll
    for (int i = 0; i < 4; ++i)
      #pragma unroll
      for (int rr = 0; rr < 4; ++rr)
        #pragma unroll
        for (int j = 0; j < 4; ++j)
          C[(size_t)(i * 16 + rr) * SEQ + j * 16] = f32_to_bf16(acc[i][j][rr]);
  }
}

// ---------------- scores = (q @ k^T) * scale, exact lower-triangle grid ----------------
// id = t*4 + b, t = triangular index over (mt,nt<=mt). 544 blocks, no dead blocks.
__global__ __launch_bounds__(256) void k_scores(const u16* __restrict__ q,
                                                const u16* __restrict__ k,
                                                float* __restrict__ w) {
  const int id = blockIdx.x;               // [0,544)
  const int b = id & 3;
  int t = id >> 2;                         // [0,136)
  int mt = (int)((sqrtf(8.0f * (float)t + 1.0f) - 1.0f) * 0.5f);
  while ((mt + 1) * (mt + 2) / 2 <= t) ++mt;
  while (mt * (mt + 1) / 2 > t) --mt;
  const int nt = t - mt * (mt + 1) / 2;
  __shared__ u16 lds[16384];
  floatx4 acc[4][4] = {};
  mfma_core(q + (size_t)b * SEQ * DIM + (size_t)mt * 128 * DIM, DIM,
            k + (size_t)b * SEQ * DIM + (size_t)nt * 128 * DIM, DIM,
            DIM / 64, lds, acc);
  const int lane = threadIdx.x & 63, wid = threadIdx.x >> 6;
  const int wm = (wid >> 1) * 64, wn = (wid & 1) * 64;
  const int lrow = lane & 15, quad = lane >> 4;
  float* C = w + (size_t)b * SEQ * SEQ
               + (size_t)(mt * 128 + wm + quad * 4) * SEQ + nt * 128 + wn + lrow;
  #pragma unroll
  for (int i = 0; i < 4; ++i)
    #pragma unroll
    for (int rr = 0; rr < 4; ++rr)
      #pragma unroll
      for (int j = 0; j < 4; ++j)
        C[(size_t)(i * 16 + rr) * SEQ + j * 16] = acc[i][j][rr] * 0.03125f;
}

// ---------------- row softmax: weights fp32 (in-place) + P bf16 ----------------
__global__ __launch_bounds__(256) void k_softmax(float* __restrict__ w,
                                                 u16* __restrict__ P) {
  const int r = blockIdx.x;
  const int i = r & (SEQ - 1);
  const int len = i + 1;
  const int plen4 = (((i >> 7) + 1) << 7) >> 2;   // P write bound / float4
  float4* srow = (float4*)(w + (size_t)r * SEQ);
  ushort4* prow = (ushort4*)(P + (size_t)r * SEQ);
  const int tid = threadIdx.x;
  const int lane = tid & 63, wid = tid >> 6;
  __shared__ float rm[4], rs[4];

  float4 e[2];
  float mx = -1e30f;
  #pragma unroll
  for (int u = 0; u < 2; ++u) {
    int q4 = tid + u * 256;
    int j0 = q4 * 4;
    float4 v = make_float4(-1e30f, -1e30f, -1e30f, -1e30f);
    if (j0 < len) {
      v = srow[q4];
      v.x = (j0 + 0 < len) ? v.x : -1e30f;
      v.y = (j0 + 1 < len) ? v.y : -1e30f;
      v.z = (j0 + 2 < len) ? v.z : -1e30f;
      v.w = (j0 + 3 < len) ? v.w : -1e30f;
    }
    e[u] = v;
    mx = fmaxf(mx, fmaxf(fmaxf(v.x, v.y), fmaxf(v.z, v.w)));
  }
  #pragma unroll
  for (int o = 32; o >= 1; o >>= 1) mx = fmaxf(mx, __shfl_xor(mx, o, 64));
  if (lane == 0) rm[wid] = mx;
  __syncthreads();
  mx = fmaxf(fmaxf(rm[0], rm[1]), fmaxf(rm[2], rm[3]));

  float sum = 0.f;
  #pragma unroll
  for (int u = 0; u < 2; ++u) {
    e[u].x = __expf(e[u].x - mx);
    e[u].y = __expf(e[u].y - mx);
    e[u].z = __expf(e[u].z - mx);
    e[u].w = __expf(e[u].w - mx);
    sum += e[u].x + e[u].y + e[u].z + e[u].w;
  }
  #pragma unroll
  for (int o = 32; o >= 1; o >>= 1) sum += __shfl_xor(sum, o, 64);
  if (lane == 0) rs[wid] = sum;
  __syncthreads();
  sum = rs[0] + rs[1] + rs[2] + rs[3];
  const float inv = 1.0f / sum;

  #pragma unroll
  for (int u = 0; u < 2; ++u) {
    int q4 = tid + u * 256;
    int j0 = q4 * 4;
    float4 v;
    v.x = (j0 + 0 < len) ? e[u].x * inv : 0.f;
    v.y = (j0 + 1 < len) ? e[u].y * inv : 0.f;
    v.z = (j0 + 2 < len) ? e[u].z * inv : 0.f;
    v.w = (j0 + 3 < len) ? e[u].w * inv : 0.f;
    srow[q4] = v;                   // full fp32 row incl. zeros (output!)
    if (q4 < plen4) {
      ushort4 p;
      p.x = f32_to_bf16(v.x); p.y = f32_to_bf16(v.y);
      p.z = f32_to_bf16(v.z); p.w = f32_to_bf16(v.w);
      prow[q4] = p;
    }
  }
}

// ---------------- att_output = P @ v (vT layout), causal K truncation ----------------
// LPT order: mt = 15 - (id>>5) so the K=2048 blocks dispatch first (no straggler
// tail). id%8 = (nt&1)*4 + b keeps each XCD on one batch + nt-parity slice of vT.
__global__ __launch_bounds__(256) void k_pv(const u16* __restrict__ P,
                                            const u16* __restrict__ vT,
                                            float* __restrict__ out) {
  const int id = blockIdx.x;               // [0,512)
  const int mt = 15 - (id >> 5);           // [0,16), descending K
  const int nt = (id >> 2) & 7;            // [0,8)
  const int b = id & 3;                    // [0,4)
  __shared__ u16 lds[16384];
  floatx4 acc[4][4] = {};
  mfma_core(P + (size_t)b * SEQ * SEQ + (size_t)mt * 128 * SEQ, SEQ,
            vT + (size_t)b * DIM * SEQ + (size_t)nt * 128 * SEQ, SEQ,
            2 * (mt + 1), lds, acc);
  const int lane = threadIdx.x & 63, wid = threadIdx.x >> 6;
  const int wm = (wid >> 1) * 64, wn = (wid & 1) * 64;
  const int lrow = lane & 15, quad = lane >> 4;
  float* C = out + (size_t)b * SEQ * DIM
                 + (size_t)(mt * 128 + wm + quad * 4) * DIM + nt * 128 + wn + lrow;
  #pragma unroll
  for (int i = 0; i < 4; ++i)
    #pragma unroll
    for (int rr = 0; rr < 4; ++rr)
      #pragma unroll
      for (int j = 0; j < 4; ++j)
        C[(size_t)(i * 16 + rr) * DIM + j * 16] = acc[i][j][rr];
}

extern "C" void kernel_launch(void* const* d_in, const int* in_sizes, int n_in,
                              void* d_out, int out_size, void* d_ws, size_t ws_size,
                              hipStream_t stream) {
  const float* x  = (const float*)d_in[0];
  const float* Wq = (const float*)d_in[1];
  const float* Wk = (const float*)d_in[2];
  const float* Wv = (const float*)d_in[3];
  float* att_out = (float*)d_out;                    // [4,2048,1024]
  float* att_w   = (float*)d_out + 8388608;          // [4,2048,2048]

  // workspace layout (bf16 elements); ~107 MB
  u16* xb = (u16*)d_ws;             // 8,388,608   x bf16
  u16* wt = xb + 8388608;           // 3,145,728   Wq^T,Wk^T,Wv^T bf16
  u16* qk = wt + 3145728;           // 16,777,216  q,k bf16
  u16* vT = qk + 16777216;          // 8,388,608   v^T per batch
  u16* P  = vT + 8388608;           // 16,777,216  softmax probs bf16

  k_prep<<<11264, 256, 0, stream>>>(x, Wq, Wk, Wv, xb, wt);
  k_proj<<<1536, 256, 0, stream>>>(xb, wt, qk, vT);
  k_scores<<<544, 256, 0, stream>>>(qk, qk + 8388608, att_w);
  k_softmax<<<8192, 256, 0, stream>>>(att_w, P);
  k_pv<<<512, 256, 0, stream>>>(P, vT, att_out);
}

// Round 5
// 276.136 us; speedup vs baseline: 1.2051x; 1.1040x over previous
//
#include <hip/hip_runtime.h>
#include <stdint.h>

#define DIM 1024
#define SEQ 2048
#define NB 4

typedef unsigned short u16;
typedef __bf16 bf16x8 __attribute__((ext_vector_type(8)));
typedef float floatx4 __attribute__((ext_vector_type(4)));

__device__ __forceinline__ u16 f32_to_bf16(float f) {
  union { float f; unsigned u; } v; v.f = f;
  unsigned r = v.u + 0x7FFFu + ((v.u >> 16) & 1u);
  return (u16)(r >> 16);
}

__device__ __forceinline__ void async16(const void* g, void* l) {
  __builtin_amdgcn_global_load_lds(
      (__attribute__((address_space(1))) unsigned int*)g,
      (__attribute__((address_space(3))) unsigned int*)l, 16, 0, 0);
}

// ---------------- prep: x fp32->bf16  +  W{q,k,v} transpose->bf16 ----------------
__global__ __launch_bounds__(256) void k_prep(const float* __restrict__ x,
                                              const float* __restrict__ Wq,
                                              const float* __restrict__ Wk,
                                              const float* __restrict__ Wv,
                                              u16* __restrict__ xb,
                                              u16* __restrict__ wt) {
  __shared__ u16 tile[32][33];
  const int bid = blockIdx.x;
  const int tid = threadIdx.x;
  if (bid < 8192) {                       // cvt: 8192 blocks x 256 x float4
    int i = bid * 256 + tid;
    float4 v = ((const float4*)x)[i];
    ushort4 o;
    o.x = f32_to_bf16(v.x); o.y = f32_to_bf16(v.y);
    o.z = f32_to_bf16(v.z); o.w = f32_to_bf16(v.w);
    ((ushort4*)xb)[i] = o;
  } else {                                // transpose: 3 x 1024 tile-blocks
    int t = bid - 8192;
    int z = t >> 10;
    int ti = t & 1023;
    int c0 = (ti & 31) * 32, r0 = (ti >> 5) * 32;
    const float* src = (z == 0) ? Wq : (z == 1) ? Wk : Wv;
    u16* d = wt + (size_t)z * DIM * DIM;
    int tx = tid & 31, ty = tid >> 5;     // 32 x 8
    #pragma unroll
    for (int dy = 0; dy < 32; dy += 8)
      tile[ty + dy][tx] = f32_to_bf16(src[(size_t)(r0 + ty + dy) * DIM + c0 + tx]);
    __syncthreads();
    #pragma unroll
    for (int dy = 0; dy < 32; dy += 8)
      d[(size_t)(c0 + ty + dy) * DIM + r0 + tx] = tile[tx][ty + dy];
  }
}

// ---------------- 128x128 MFMA GEMM core (A[m][k], Bt[n][k], bf16) ----------------
// LDS layout is XOR-swizzled: 8-elem granule c8 of row r is stored at granule
// c8 ^ (r&7). Staging keeps the wave-uniform global_load_lds pattern by
// permuting the *global* source column per lane; fragment reads then hit all
// 32 banks at 2 lanes/bank (free) instead of banks 0-15 at 16-way.
__device__ __forceinline__ void mfma_core(const u16* __restrict__ A, int lda,
                                          const u16* __restrict__ Bt, int ldb,
                                          int ktiles, u16* lds,
                                          floatx4 acc[4][4]) {
  const int tid = threadIdx.x;
  const int lane = tid & 63;
  const int wid = tid >> 6;
  u16* lds_a = lds;            // 128 x 64 (swizzled granules)
  u16* lds_b = lds + 8192;     // 128 x 64 (n-major, swizzled granules)

  // staging: lane covers row (wid*32 + c*8 + (lane>>3)), granule (lane&7).
  // row&7 == (lane>>3)&7, so swizzled source granule = (lane&7) ^ ((lane>>3)&7).
  const int srow = lane >> 3;
  const int sg = (lane & 7) ^ (srow & 7);
  const u16* ag = A + (size_t)(wid * 32 + srow) * lda + sg * 8;
  const u16* bg = Bt + (size_t)(wid * 32 + srow) * ldb + sg * 8;
  u16* la = lds_a + wid * 2048;  // wave-uniform
  u16* lb = lds_b + wid * 2048;

  const int wm = (wid >> 1) * 64, wn = (wid & 1) * 64;
  const int lrow = lane & 15, quad = lane >> 4;
  const int s = lrow & 7;
  // fragment granule for (quad, ks): (quad + 4*ks) ^ s ; ks=1 flips bit 2.
  const int g0 = (quad ^ s) * 8;
  const int g1 = ((quad + 4) ^ s) * 8;
  const u16* pa = lds_a + (wm + lrow) * 64;
  const u16* pb = lds_b + (wn + lrow) * 64;

  for (int kt = 0; kt < ktiles; ++kt) {
    #pragma unroll
    for (int c = 0; c < 4; ++c) {
      async16(ag + (size_t)c * 8 * lda, la + c * 512);
      async16(bg + (size_t)c * 8 * ldb, lb + c * 512);
    }
    ag += 64; bg += 64;
    __syncthreads();
    #pragma unroll
    for (int ks = 0; ks < 2; ++ks) {
      const int g = ks ? g1 : g0;
      bf16x8 af[4], bfr[4];
      #pragma unroll
      for (int t = 0; t < 4; ++t) af[t] = *(const bf16x8*)(pa + t * 1024 + g);
      #pragma unroll
      for (int t = 0; t < 4; ++t) bfr[t] = *(const bf16x8*)(pb + t * 1024 + g);
      #pragma unroll
      for (int i = 0; i < 4; ++i)
        #pragma unroll
        for (int j = 0; j < 4; ++j)
          acc[i][j] = __builtin_amdgcn_mfma_f32_16x16x32_bf16(af[i], bfr[j],
                                                              acc[i][j], 0, 0, 0);
    }
    __syncthreads();
  }
}

// ---------------- all projections: q,k (= x@W) and vT (= Wv^T@x^T) ----------------
__global__ __launch_bounds__(256) void k_proj(const u16* __restrict__ xb,
                                              const u16* __restrict__ wt,
                                              u16* __restrict__ qk,
                                              u16* __restrict__ vT) {
  const int id = blockIdx.x;               // [0,1536)
  const int z2 = id >> 9;                  // 0,1,2
  const int r = id & 511;
  const int g = (r >> 6) * 8 + (r & 7);    // [0,64) shared-tile group
  const int h = (r >> 3) & 7;              // [0,8)
  __shared__ u16 lds[16384];
  floatx4 acc[4][4] = {};
  const u16 *A, *Bt;
  if (z2 < 2) {
    A = xb + (size_t)g * 128 * DIM;
    Bt = wt + (size_t)z2 * DIM * DIM + (size_t)h * 128 * DIM;
  } else {
    A = wt + (size_t)2 * DIM * DIM + (size_t)h * 128 * DIM;
    Bt = xb + (size_t)g * 128 * DIM;
  }
  mfma_core(A, DIM, Bt, DIM, DIM / 64, lds, acc);
  const int lane = threadIdx.x & 63, wid = threadIdx.x >> 6;
  const int wm = (wid >> 1) * 64, wn = (wid & 1) * 64;
  const int lrow = lane & 15, quad = lane >> 4;
  if (z2 < 2) {
    u16* C = qk + (size_t)z2 * (NB * SEQ * DIM)
                + (size_t)(g * 128 + wm + quad * 4) * DIM + h * 128 + wn + lrow;
    #pragma unroll
    for (int i = 0; i < 4; ++i)
      #pragma unroll
      for (int rr = 0; rr < 4; ++rr)
        #pragma unroll
        for (int j = 0; j < 4; ++j)
          C[(size_t)(i * 16 + rr) * DIM + j * 16] = f32_to_bf16(acc[i][j][rr]);
  } else {
    const int t0 = g * 128;
    const int b = t0 >> 11, s0 = t0 & 2047;
    u16* C = vT + (size_t)b * (DIM * SEQ)
                + (size_t)(h * 128 + wm + quad * 4) * SEQ + s0 + wn + lrow;
    #pragma unroll
    for (int i = 0; i < 4; ++i)
      #pragma unroll
      for (int rr = 0; rr < 4; ++rr)
        #pragma unroll
        for (int j = 0; j < 4; ++j)
          C[(size_t)(i * 16 + rr) * SEQ + j * 16] = f32_to_bf16(acc[i][j][rr]);
  }
}

// ---------------- scores = (q @ k^T) * scale, exact lower-triangle grid ----------------
__global__ __launch_bounds__(256) void k_scores(const u16* __restrict__ q,
                                                const u16* __restrict__ k,
                                                float* __restrict__ w) {
  const int id = blockIdx.x;               // [0,544)
  const int b = id & 3;
  int t = id >> 2;                         // [0,136)
  int mt = (int)((sqrtf(8.0f * (float)t + 1.0f) - 1.0f) * 0.5f);
  while ((mt + 1) * (mt + 2) / 2 <= t) ++mt;
  while (mt * (mt + 1) / 2 > t) --mt;
  const int nt = t - mt * (mt + 1) / 2;
  __shared__ u16 lds[16384];
  floatx4 acc[4][4] = {};
  mfma_core(q + (size_t)b * SEQ * DIM + (size_t)mt * 128 * DIM, DIM,
            k + (size_t)b * SEQ * DIM + (size_t)nt * 128 * DIM, DIM,
            DIM / 64, lds, acc);
  const int lane = threadIdx.x & 63, wid = threadIdx.x >> 6;
  const int wm = (wid >> 1) * 64, wn = (wid & 1) * 64;
  const int lrow = lane & 15, quad = lane >> 4;
  float* C = w + (size_t)b * SEQ * SEQ
               + (size_t)(mt * 128 + wm + quad * 4) * SEQ + nt * 128 + wn + lrow;
  #pragma unroll
  for (int i = 0; i < 4; ++i)
    #pragma unroll
    for (int rr = 0; rr < 4; ++rr)
      #pragma unroll
      for (int j = 0; j < 4; ++j)
        C[(size_t)(i * 16 + rr) * SEQ + j * 16] = acc[i][j][rr] * 0.03125f;
}

// ---------------- row softmax: weights fp32 (in-place) + P bf16 ----------------
__global__ __launch_bounds__(256) void k_softmax(float* __restrict__ w,
                                                 u16* __restrict__ P) {
  const int r = blockIdx.x;
  const int i = r & (SEQ - 1);
  const int len = i + 1;
  const int plen4 = (((i >> 7) + 1) << 7) >> 2;   // P write bound / float4
  float4* srow = (float4*)(w + (size_t)r * SEQ);
  ushort4* prow = (ushort4*)(P + (size_t)r * SEQ);
  const int tid = threadIdx.x;
  const int lane = tid & 63, wid = tid >> 6;
  __shared__ float rm[4], rs[4];

  float4 e[2];
  float mx = -1e30f;
  #pragma unroll
  for (int u = 0; u < 2; ++u) {
    int q4 = tid + u * 256;
    int j0 = q4 * 4;
    float4 v = make_float4(-1e30f, -1e30f, -1e30f, -1e30f);
    if (j0 < len) {
      v = srow[q4];
      v.x = (j0 + 0 < len) ? v.x : -1e30f;
      v.y = (j0 + 1 < len) ? v.y : -1e30f;
      v.z = (j0 + 2 < len) ? v.z : -1e30f;
      v.w = (j0 + 3 < len) ? v.w : -1e30f;
    }
    e[u] = v;
    mx = fmaxf(mx, fmaxf(fmaxf(v.x, v.y), fmaxf(v.z, v.w)));
  }
  #pragma unroll
  for (int o = 32; o >= 1; o >>= 1) mx = fmaxf(mx, __shfl_xor(mx, o, 64));
  if (lane == 0) rm[wid] = mx;
  __syncthreads();
  mx = fmaxf(fmaxf(rm[0], rm[1]), fmaxf(rm[2], rm[3]));

  float sum = 0.f;
  #pragma unroll
  for (int u = 0; u < 2; ++u) {
    e[u].x = __expf(e[u].x - mx);
    e[u].y = __expf(e[u].y - mx);
    e[u].z = __expf(e[u].z - mx);
    e[u].w = __expf(e[u].w - mx);
    sum += e[u].x + e[u].y + e[u].z + e[u].w;
  }
  #pragma unroll
  for (int o = 32; o >= 1; o >>= 1) sum += __shfl_xor(sum, o, 64);
  if (lane == 0) rs[wid] = sum;
  __syncthreads();
  sum = rs[0] + rs[1] + rs[2] + rs[3];
  const float inv = 1.0f / sum;

  #pragma unroll
  for (int u = 0; u < 2; ++u) {
    int q4 = tid + u * 256;
    int j0 = q4 * 4;
    float4 v;
    v.x = (j0 + 0 < len) ? e[u].x * inv : 0.f;
    v.y = (j0 + 1 < len) ? e[u].y * inv : 0.f;
    v.z = (j0 + 2 < len) ? e[u].z * inv : 0.f;
    v.w = (j0 + 3 < len) ? e[u].w * inv : 0.f;
    srow[q4] = v;                   // full fp32 row incl. zeros (output!)
    if (q4 < plen4) {
      ushort4 p;
      p.x = f32_to_bf16(v.x); p.y = f32_to_bf16(v.y);
      p.z = f32_to_bf16(v.z); p.w = f32_to_bf16(v.w);
      prow[q4] = p;
    }
  }
}

// ---------------- att_output = P @ v (vT layout), causal K truncation ----------------
__global__ __launch_bounds__(256) void k_pv(const u16* __restrict__ P,
                                            const u16* __restrict__ vT,
                                            float* __restrict__ out) {
  const int id = blockIdx.x;               // [0,512)
  const int mt = 15 - (id >> 5);           // [0,16), descending K (LPT)
  const int nt = (id >> 2) & 7;            // [0,8)
  const int b = id & 3;                    // [0,4)
  __shared__ u16 lds[16384];
  floatx4 acc[4][4] = {};
  mfma_core(P + (size_t)b * SEQ * SEQ + (size_t)mt * 128 * SEQ, SEQ,
            vT + (size_t)b * DIM * SEQ + (size_t)nt * 128 * SEQ, SEQ,
            2 * (mt + 1), lds, acc);
  const int lane = threadIdx.x & 63, wid = threadIdx.x >> 6;
  const int wm = (wid >> 1) * 64, wn = (wid & 1) * 64;
  const int lrow = lane & 15, quad = lane >> 4;
  float* C = out + (size_t)b * SEQ * DIM
                 + (size_t)(mt * 128 + wm + quad * 4) * DIM + nt * 128 + wn + lrow;
  #pragma unroll
  for (int i = 0; i < 4; ++i)
    #pragma unroll
    for (int rr = 0; rr < 4; ++rr)
      #pragma unroll
      for (int j = 0; j < 4; ++j)
        C[(size_t)(i * 16 + rr) * DIM + j * 16] = acc[i][j][rr];
}

extern "C" void kernel_launch(void* const* d_in, const int* in_sizes, int n_in,
                              void* d_out, int out_size, void* d_ws, size_t ws_size,
                              hipStream_t stream) {
  const float* x  = (const float*)d_in[0];
  const float* Wq = (const float*)d_in[1];
  const float* Wk = (const float*)d_in[2];
  const float* Wv = (const float*)d_in[3];
  float* att_out = (float*)d_out;                    // [4,2048,1024]
  float* att_w   = (float*)d_out + 8388608;          // [4,2048,2048]

  // workspace layout (bf16 elements); ~107 MB
  u16* xb = (u16*)d_ws;             // 8,388,608   x bf16
  u16* wt = xb + 8388608;           // 3,145,728   Wq^T,Wk^T,Wv^T bf16
  u16* qk = wt + 3145728;           // 16,777,216  q,k bf16
  u16* vT = qk + 16777216;          // 8,388,608   v^T per batch
  u16* P  = vT + 8388608;           // 16,777,216  softmax probs bf16

  k_prep<<<11264, 256, 0, stream>>>(x, Wq, Wk, Wv, xb, wt);
  k_proj<<<1536, 256, 0, stream>>>(xb, wt, qk, vT);
  k_scores<<<544, 256, 0, stream>>>(qk, qk + 8388608, att_w);
  k_softmax<<<8192, 256, 0, stream>>>(att_w, P);
  k_pv<<<512, 256, 0, stream>>>(P, vT, att_out);
}

// Round 6
// 273.661 us; speedup vs baseline: 1.2160x; 1.0090x over previous
//
#include <hip/hip_runtime.h>
#include <stdint.h>

#define DIM 1024
#define SEQ 2048
#define NB 4

typedef unsigned short u16;
typedef __bf16 bf16x8 __attribute__((ext_vector_type(8)));
typedef float floatx4 __attribute__((ext_vector_type(4)));

__device__ __forceinline__ u16 f32_to_bf16(float f) {
  union { float f; unsigned u; } v; v.f = f;
  unsigned r = v.u + 0x7FFFu + ((v.u >> 16) & 1u);
  return (u16)(r >> 16);
}

__device__ __forceinline__ void async16(const void* g, void* l) {
  __builtin_amdgcn_global_load_lds(
      (__attribute__((address_space(1))) unsigned int*)g,
      (__attribute__((address_space(3))) unsigned int*)l, 16, 0, 0);
}

// ---------------- prep: x fp32->bf16 (16B stores)  +  W transpose ----------------
__global__ __launch_bounds__(256) void k_prep(const float* __restrict__ x,
                                              const float* __restrict__ Wq,
                                              const float* __restrict__ Wk,
                                              const float* __restrict__ Wv,
                                              u16* __restrict__ xb,
                                              u16* __restrict__ wt) {
  __shared__ u16 tile[32][33];
  const int bid = blockIdx.x;
  const int tid = threadIdx.x;
  if (bid < 4096) {                       // cvt: 4096 blocks x 256 x 8 floats
    int i = bid * 256 + tid;
    float4 a = ((const float4*)x)[i * 2];
    float4 b = ((const float4*)x)[i * 2 + 1];
    ushort4 o0, o1;
    o0.x = f32_to_bf16(a.x); o0.y = f32_to_bf16(a.y);
    o0.z = f32_to_bf16(a.z); o0.w = f32_to_bf16(a.w);
    o1.x = f32_to_bf16(b.x); o1.y = f32_to_bf16(b.y);
    o1.z = f32_to_bf16(b.z); o1.w = f32_to_bf16(b.w);
    ((ushort4*)xb)[i * 2] = o0;
    ((ushort4*)xb)[i * 2 + 1] = o1;
  } else {                                // transpose: 3 x 1024 tile-blocks
    int t = bid - 4096;
    int z = t >> 10;
    int ti = t & 1023;
    int c0 = (ti & 31) * 32, r0 = (ti >> 5) * 32;
    const float* src = (z == 0) ? Wq : (z == 1) ? Wk : Wv;
    u16* d = wt + (size_t)z * DIM * DIM;
    int tx = tid & 31, ty = tid >> 5;     // 32 x 8
    #pragma unroll
    for (int dy = 0; dy < 32; dy += 8)
      tile[ty + dy][tx] = f32_to_bf16(src[(size_t)(r0 + ty + dy) * DIM + c0 + tx]);
    __syncthreads();
    #pragma unroll
    for (int dy = 0; dy < 32; dy += 8)
      d[(size_t)(c0 + ty + dy) * DIM + r0 + tx] = tile[tx][ty + dy];
  }
}

// ---------------- BK=64 MFMA core (proj: high block count, 32KB LDS) ----------------
__device__ __forceinline__ void mfma_core(const u16* __restrict__ A, int lda,
                                          const u16* __restrict__ Bt, int ldb,
                                          int ktiles, u16* lds,
                                          floatx4 acc[4][4]) {
  const int tid = threadIdx.x;
  const int lane = tid & 63;
  const int wid = tid >> 6;
  u16* lds_a = lds;            // 128 x 64 (swizzled granules)
  u16* lds_b = lds + 8192;

  const int srow = lane >> 3;
  const int sg = (lane & 7) ^ (srow & 7);
  const u16* ag = A + (size_t)(wid * 32 + srow) * lda + sg * 8;
  const u16* bg = Bt + (size_t)(wid * 32 + srow) * ldb + sg * 8;
  u16* la = lds_a + wid * 2048;
  u16* lb = lds_b + wid * 2048;

  const int wm = (wid >> 1) * 64, wn = (wid & 1) * 64;
  const int lrow = lane & 15, quad = lane >> 4;
  const int s = lrow & 7;
  const int g0 = (quad ^ s) * 8;
  const int g1 = ((quad + 4) ^ s) * 8;
  const u16* pa = lds_a + (wm + lrow) * 64;
  const u16* pb = lds_b + (wn + lrow) * 64;

  for (int kt = 0; kt < ktiles; ++kt) {
    #pragma unroll
    for (int c = 0; c < 4; ++c) {
      async16(ag + (size_t)c * 8 * lda, la + c * 512);
      async16(bg + (size_t)c * 8 * ldb, lb + c * 512);
    }
    ag += 64; bg += 64;
    __syncthreads();
    #pragma unroll
    for (int ks = 0; ks < 2; ++ks) {
      const int g = ks ? g1 : g0;
      bf16x8 af[4], bfr[4];
      #pragma unroll
      for (int t = 0; t < 4; ++t) af[t] = *(const bf16x8*)(pa + t * 1024 + g);
      #pragma unroll
      for (int t = 0; t < 4; ++t) bfr[t] = *(const bf16x8*)(pb + t * 1024 + g);
      #pragma unroll
      for (int i = 0; i < 4; ++i)
        #pragma unroll
        for (int j = 0; j < 4; ++j)
          acc[i][j] = __builtin_amdgcn_mfma_f32_16x16x32_bf16(af[i], bfr[j],
                                                              acc[i][j], 0, 0, 0);
    }
    __syncthreads();
  }
}

// ---------------- BK=128 MFMA core (scores/pv: grid-capped residency) ----------------
// 64 KB LDS (2 blocks/CU — these kernels are already grid-capped at 2), one
// barrier pair per 128-K: half the vmcnt(0)+barrier drains of the BK=64 core.
// kchunks counts 128-wide K chunks.
__device__ __forceinline__ void mfma_core128(const u16* __restrict__ A, int lda,
                                             const u16* __restrict__ Bt, int ldb,
                                             int kchunks, u16* lds,
                                             floatx4 acc[4][4]) {
  const int tid = threadIdx.x;
  const int lane = tid & 63;
  const int wid = tid >> 6;
  u16* lds_a = lds;            // 128 x 128 (swizzled granules)
  u16* lds_b = lds + 16384;

  // staging: per issue c, 64 lanes cover 4 rows x 16 granules (1 KB).
  // global granule = slot ^ (row&7); row = wid*32 + c*4 + (lane>>4).
  const int srow4 = lane >> 4;          // 0..3
  const int sgr = lane & 15;
  const int gbase = sgr ^ srow4;        // even c
  const u16* ag0 = A + (size_t)(wid * 32 + srow4) * lda + gbase * 8;
  const u16* ag1 = A + (size_t)(wid * 32 + srow4) * lda + (gbase ^ 4) * 8;
  const u16* bg0 = Bt + (size_t)(wid * 32 + srow4) * ldb + gbase * 8;
  const u16* bg1 = Bt + (size_t)(wid * 32 + srow4) * ldb + (gbase ^ 4) * 8;
  u16* la = lds_a + wid * 4096;         // 32 rows x 128
  u16* lb = lds_b + wid * 4096;

  const int wm = (wid >> 1) * 64, wn = (wid & 1) * 64;
  const int lrow = lane & 15, quad = lane >> 4;
  const int s = lrow & 7;
  const u16* pa = lds_a + (wm + lrow) * 128;
  const u16* pb = lds_b + (wn + lrow) * 128;

  for (int kt = 0; kt < kchunks; ++kt) {
    #pragma unroll
    for (int c = 0; c < 8; ++c) {
      const u16* sa = ((c & 1) ? ag1 : ag0) + (size_t)(c * 4) * lda;
      async16(sa, la + c * 512);
    }
    #pragma unroll
    for (int c = 0; c < 8; ++c) {
      const u16* sb = ((c & 1) ? bg1 : bg0) + (size_t)(c * 4) * ldb;
      async16(sb, lb + c * 512);
    }
    ag0 += 128; ag1 += 128; bg0 += 128; bg1 += 128;
    __syncthreads();
    #pragma unroll
    for (int ks = 0; ks < 4; ++ks) {
      const int g = (((ks << 2) | quad) ^ s) << 3;
      bf16x8 af[4], bfr[4];
      #pragma unroll
      for (int t = 0; t < 4; ++t) af[t] = *(const bf16x8*)(pa + t * 2048 + g);
      #pragma unroll
      for (int t = 0; t < 4; ++t) bfr[t] = *(const bf16x8*)(pb + t * 2048 + g);
      #pragma unroll
      for (int i = 0; i < 4; ++i)
        #pragma unroll
        for (int j = 0; j < 4; ++j)
          acc[i][j] = __builtin_amdgcn_mfma_f32_16x16x32_bf16(af[i], bfr[j],
                                                              acc[i][j], 0, 0, 0);
    }
    __syncthreads();
  }
}

// ---------------- all projections: q,k (= x@W) and vT (= Wv^T@x^T) ----------------
__global__ __launch_bounds__(256) void k_proj(const u16* __restrict__ xb,
                                              const u16* __restrict__ wt,
                                              u16* __restrict__ qk,
                                              u16* __restrict__ vT) {
  const int id = blockIdx.x;               // [0,1536)
  const int z2 = id >> 9;                  // 0,1,2
  const int r = id & 511;
  const int g = (r >> 6) * 8 + (r & 7);    // [0,64) shared-tile group
  const int h = (r >> 3) & 7;              // [0,8)
  __shared__ u16 lds[16384];
  floatx4 acc[4][4] = {};
  const u16 *A, *Bt;
  if (z2 < 2) {
    A = xb + (size_t)g * 128 * DIM;
    Bt = wt + (size_t)z2 * DIM * DIM + (size_t)h * 128 * DIM;
  } else {
    A = wt + (size_t)2 * DIM * DIM + (size_t)h * 128 * DIM;
    Bt = xb + (size_t)g * 128 * DIM;
  }
  mfma_core(A, DIM, Bt, DIM, DIM / 64, lds, acc);
  const int lane = threadIdx.x & 63, wid = threadIdx.x >> 6;
  const int wm = (wid >> 1) * 64, wn = (wid & 1) * 64;
  const int lrow = lane & 15, quad = lane >> 4;
  if (z2 < 2) {
    u16* C = qk + (size_t)z2 * (NB * SEQ * DIM)
                + (size_t)(g * 128 + wm + quad * 4) * DIM + h * 128 + wn + lrow;
    #pragma unroll
    for (int i = 0; i < 4; ++i)
      #pragma unroll
      for (int rr = 0; rr < 4; ++rr)
        #pragma unroll
        for (int j = 0; j < 4; ++j)
          C[(size_t)(i * 16 + rr) * DIM + j * 16] = f32_to_bf16(acc[i][j][rr]);
  } else {
    const int t0 = g * 128;
    const int b = t0 >> 11, s0 = t0 & 2047;
    u16* C = vT + (size_t)b * (DIM * SEQ)
                + (size_t)(h * 128 + wm + quad * 4) * SEQ + s0 + wn + lrow;
    #pragma unroll
    for (int i = 0; i < 4; ++i)
      #pragma unroll
      for (int rr = 0; rr < 4; ++rr)
        #pragma unroll
        for (int j = 0; j < 4; ++j)
          C[(size_t)(i * 16 + rr) * SEQ + j * 16] = f32_to_bf16(acc[i][j][rr]);
  }
}

// ---------------- scores = (q @ k^T) * scale, exact lower-triangle grid ----------------
__global__ __launch_bounds__(256) void k_scores(const u16* __restrict__ q,
                                                const u16* __restrict__ k,
                                                float* __restrict__ w) {
  const int id = blockIdx.x;               // [0,544)
  const int b = id & 3;
  int t = id >> 2;                         // [0,136)
  int mt = (int)((sqrtf(8.0f * (float)t + 1.0f) - 1.0f) * 0.5f);
  while ((mt + 1) * (mt + 2) / 2 <= t) ++mt;
  while (mt * (mt + 1) / 2 > t) --mt;
  const int nt = t - mt * (mt + 1) / 2;
  __shared__ u16 lds[32768];
  floatx4 acc[4][4] = {};
  mfma_core128(q + (size_t)b * SEQ * DIM + (size_t)mt * 128 * DIM, DIM,
               k + (size_t)b * SEQ * DIM + (size_t)nt * 128 * DIM, DIM,
               DIM / 128, lds, acc);
  const int lane = threadIdx.x & 63, wid = threadIdx.x >> 6;
  const int wm = (wid >> 1) * 64, wn = (wid & 1) * 64;
  const int lrow = lane & 15, quad = lane >> 4;
  float* C = w + (size_t)b * SEQ * SEQ
               + (size_t)(mt * 128 + wm + quad * 4) * SEQ + nt * 128 + wn + lrow;
  #pragma unroll
  for (int i = 0; i < 4; ++i)
    #pragma unroll
    for (int rr = 0; rr < 4; ++rr)
      #pragma unroll
      for (int j = 0; j < 4; ++j)
        C[(size_t)(i * 16 + rr) * SEQ + j * 16] = acc[i][j][rr] * 0.03125f;
}

// ---------------- row softmax: weights fp32 (in-place) + P bf16 ----------------
__global__ __launch_bounds__(256) void k_softmax(float* __restrict__ w,
                                                 u16* __restrict__ P) {
  const int r = blockIdx.x;
  const int i = r & (SEQ - 1);
  const int len = i + 1;
  const int plen4 = (((i >> 7) + 1) << 7) >> 2;   // P write bound / float4
  float4* srow = (float4*)(w + (size_t)r * SEQ);
  ushort4* prow = (ushort4*)(P + (size_t)r * SEQ);
  const int tid = threadIdx.x;
  const int lane = tid & 63, wid = tid >> 6;
  __shared__ float rm[4], rs[4];

  float4 e[2];
  float mx = -1e30f;
  #pragma unroll
  for (int u = 0; u < 2; ++u) {
    int q4 = tid + u * 256;
    int j0 = q4 * 4;
    float4 v = make_float4(-1e30f, -1e30f, -1e30f, -1e30f);
    if (j0 < len) {
      v = srow[q4];
      v.x = (j0 + 0 < len) ? v.x : -1e30f;
      v.y = (j0 + 1 < len) ? v.y : -1e30f;
      v.z = (j0 + 2 < len) ? v.z : -1e30f;
      v.w = (j0 + 3 < len) ? v.w : -1e30f;
    }
    e[u] = v;
    mx = fmaxf(mx, fmaxf(fmaxf(v.x, v.y), fmaxf(v.z, v.w)));
  }
  #pragma unroll
  for (int o = 32; o >= 1; o >>= 1) mx = fmaxf(mx, __shfl_xor(mx, o, 64));
  if (lane == 0) rm[wid] = mx;
  __syncthreads();
  mx = fmaxf(fmaxf(rm[0], rm[1]), fmaxf(rm[2], rm[3]));

  float sum = 0.f;
  #pragma unroll
  for (int u = 0; u < 2; ++u) {
    e[u].x = __expf(e[u].x - mx);
    e[u].y = __expf(e[u].y - mx);
    e[u].z = __expf(e[u].z - mx);
    e[u].w = __expf(e[u].w - mx);
    sum += e[u].x + e[u].y + e[u].z + e[u].w;
  }
  #pragma unroll
  for (int o = 32; o >= 1; o >>= 1) sum += __shfl_xor(sum, o, 64);
  if (lane == 0) rs[wid] = sum;
  __syncthreads();
  sum = rs[0] + rs[1] + rs[2] + rs[3];
  const float inv = 1.0f / sum;

  #pragma unroll
  for (int u = 0; u < 2; ++u) {
    int q4 = tid + u * 256;
    int j0 = q4 * 4;
    float4 v;
    v.x = (j0 + 0 < len) ? e[u].x * inv : 0.f;
    v.y = (j0 + 1 < len) ? e[u].y * inv : 0.f;
    v.z = (j0 + 2 < len) ? e[u].z * inv : 0.f;
    v.w = (j0 + 3 < len) ? e[u].w * inv : 0.f;
    srow[q4] = v;                   // full fp32 row incl. zeros (output!)
    if (q4 < plen4) {
      ushort4 p;
      p.x = f32_to_bf16(v.x); p.y = f32_to_bf16(v.y);
      p.z = f32_to_bf16(v.z); p.w = f32_to_bf16(v.w);
      prow[q4] = p;
    }
  }
}

// ---------------- att_output = P @ v (vT layout), causal K truncation ----------------
__global__ __launch_bounds__(256) void k_pv(const u16* __restrict__ P,
                                            const u16* __restrict__ vT,
                                            float* __restrict__ out) {
  const int id = blockIdx.x;               // [0,512)
  const int mt = 15 - (id >> 5);           // [0,16), descending K (LPT)
  const int nt = (id >> 2) & 7;            // [0,8)
  const int b = id & 3;                    // [0,4)
  __shared__ u16 lds[32768];
  floatx4 acc[4][4] = {};
  mfma_core128(P + (size_t)b * SEQ * SEQ + (size_t)mt * 128 * SEQ, SEQ,
               vT + (size_t)b * DIM * SEQ + (size_t)nt * 128 * SEQ, SEQ,
               mt + 1, lds, acc);
  const int lane = threadIdx.x & 63, wid = threadIdx.x >> 6;
  const int wm = (wid >> 1) * 64, wn = (wid & 1) * 64;
  const int lrow = lane & 15, quad = lane >> 4;
  float* C = out + (size_t)b * SEQ * DIM
                 + (size_t)(mt * 128 + wm + quad * 4) * DIM + nt * 128 + wn + lrow;
  #pragma unroll
  for (int i = 0; i < 4; ++i)
    #pragma unroll
    for (int rr = 0; rr < 4; ++rr)
      #pragma unroll
      for (int j = 0; j < 4; ++j)
        C[(size_t)(i * 16 + rr) * DIM + j * 16] = acc[i][j][rr];
}

extern "C" void kernel_launch(void* const* d_in, const int* in_sizes, int n_in,
                              void* d_out, int out_size, void* d_ws, size_t ws_size,
                              hipStream_t stream) {
  const float* x  = (const float*)d_in[0];
  const float* Wq = (const float*)d_in[1];
  const float* Wk = (const float*)d_in[2];
  const float* Wv = (const float*)d_in[3];
  float* att_out = (float*)d_out;                    // [4,2048,1024]
  float* att_w   = (float*)d_out + 8388608;          // [4,2048,2048]

  // workspace layout (bf16 elements); ~107 MB
  u16* xb = (u16*)d_ws;             // 8,388,608   x bf16
  u16* wt = xb + 8388608;           // 3,145,728   Wq^T,Wk^T,Wv^T bf16
  u16* qk = wt + 3145728;           // 16,777,216  q,k bf16
  u16* vT = qk + 16777216;          // 8,388,608   v^T per batch
  u16* P  = vT + 8388608;           // 16,777,216  softmax probs bf16

  k_prep<<<7168, 256, 0, stream>>>(x, Wq, Wk, Wv, xb, wt);
  k_proj<<<1536, 256, 0, stream>>>(xb, wt, qk, vT);
  k_scores<<<544, 256, 0, stream>>>(qk, qk + 8388608, att_w);
  k_softmax<<<8192, 256, 0, stream>>>(att_w, P);
  k_pv<<<512, 256, 0, stream>>>(P, vT, att_out);
}